// Round 4
// baseline (452.391 us; speedup 1.0000x reference)
//
#include <hip/hip_runtime.h>
#include <hip/hip_bf16.h>

typedef __attribute__((ext_vector_type(4))) float f32x4;
typedef __attribute__((ext_vector_type(8))) short bf16x8;

#define M_DIM 8192
#define N_DIM 4096
#define K_DIM 4096
#define NH 8
#define R_DIM 16

__device__ __forceinline__ unsigned short f2bf(float f) {
  union { float f; unsigned int u; } v; v.f = f;
  unsigned int r = v.u + 0x7fffu + ((v.u >> 16) & 1u);  // RNE
  return (unsigned short)(r >> 16);
}

__device__ __forceinline__ void gll16(const void* gptr, void* lptr) {
  __builtin_amdgcn_global_load_lds(
      (const __attribute__((address_space(1))) void*)gptr,
      (__attribute__((address_space(3))) void*)lptr, 16, 0, 0);
}

__device__ __forceinline__ unsigned lds_addr(const void* p) {
  return (unsigned)(uintptr_t)(const __attribute__((address_space(3))) void*)p;
}

#define BAR() do { __builtin_amdgcn_sched_barrier(0); asm volatile("" ::: "memory"); \
  __builtin_amdgcn_s_barrier(); asm volatile("" ::: "memory"); \
  __builtin_amdgcn_sched_barrier(0); } while (0)
#define LGKM(N) do { asm volatile("s_waitcnt lgkmcnt(" #N ")" ::: "memory"); \
  __builtin_amdgcn_sched_barrier(0); } while (0)
#define VMC(N) do { asm volatile("s_waitcnt vmcnt(" #N ")" ::: "memory"); \
  __builtin_amdgcn_sched_barrier(0); } while (0)
#define DSR(D, ADDR, IMM) asm volatile("ds_read_b128 %0, %1 offset:%2" \
  : "=&v"(D) : "v"(ADDR), "i"(IMM))

// ---------------- Kernel 1: cast x (f32) -> bf16 ----------------
__global__ void k_cast_bf16(const float* __restrict__ in,
                            unsigned short* __restrict__ out, int n4) {
  int i = blockIdx.x * 256 + threadIdx.x;
  if (i >= n4) return;
  float4 v = reinterpret_cast<const float4*>(in)[i];
  ushort4 o;
  o.x = f2bf(v.x); o.y = f2bf(v.y); o.z = f2bf(v.z); o.w = f2bf(v.w);
  reinterpret_cast<ushort4*>(out)[i] = o;
}

// ---------------- Kernel 2: HA = s * (H @ A) ----------------
__global__ void k_ha(const float* __restrict__ A, const float* __restrict__ H,
                     const float* __restrict__ s, float* __restrict__ HA) {
  int idx = blockIdx.x * 256 + threadIdx.x;
  int dc = idx & 1023;
  int q  = (idx >> 10) & 15;
  int h  = idx >> 14;
  const float* Ah = A + (long)h * R_DIM * K_DIM;
  const float* Hh = H + h * R_DIM * R_DIM + q * R_DIM;
  f32x4 acc = {0.f, 0.f, 0.f, 0.f};
  #pragma unroll
  for (int r = 0; r < R_DIM; ++r) {
    float hv = Hh[r];
    float4 av = reinterpret_cast<const float4*>(Ah + (long)r * K_DIM)[dc];
    acc.x += hv * av.x; acc.y += hv * av.y; acc.z += hv * av.z; acc.w += hv * av.w;
  }
  float sv = s[h];
  float4 o; o.x = acc.x * sv; o.y = acc.y * sv; o.z = acc.z * sv; o.w = acc.w * sv;
  reinterpret_cast<float4*>(HA + ((long)h * R_DIM + q) * K_DIM)[dc] = o;
}

// ---------------- Kernel 3: Weff = bf16(W + Bcat @ HA) ----------------
__global__ void k_weff(const float* __restrict__ W, const float* __restrict__ Bm,
                       const float* __restrict__ HA, unsigned short* __restrict__ Weff) {
  __shared__ float bsh[8][128];
  int o0 = blockIdx.x * 8;
  int c4 = blockIdx.y * 256;
  int t = threadIdx.x;
  for (int i = t; i < 1024; i += 256) {
    int r = i >> 7, hq = i & 127;
    int h = hq >> 4, q = hq & 15;
    bsh[r][hq] = Bm[((long)h * N_DIM + (o0 + r)) * R_DIM + q];
  }
  __syncthreads();
  int dc = c4 + t;
  f32x4 acc[8];
  #pragma unroll
  for (int r = 0; r < 8; ++r) {
    float4 w = reinterpret_cast<const float4*>(W + (long)(o0 + r) * K_DIM)[dc];
    acc[r].x = w.x; acc[r].y = w.y; acc[r].z = w.z; acc[r].w = w.w;
  }
  for (int hq = 0; hq < 128; ++hq) {
    float4 hv = reinterpret_cast<const float4*>(HA + (long)hq * K_DIM)[dc];
    #pragma unroll
    for (int r = 0; r < 8; ++r) {
      float bv = bsh[r][hq];
      acc[r].x += bv * hv.x; acc[r].y += bv * hv.y;
      acc[r].z += bv * hv.z; acc[r].w += bv * hv.w;
    }
  }
  #pragma unroll
  for (int r = 0; r < 8; ++r) {
    ushort4 ov;
    ov.x = f2bf(acc[r].x); ov.y = f2bf(acc[r].y);
    ov.z = f2bf(acc[r].z); ov.w = f2bf(acc[r].w);
    reinterpret_cast<ushort4*>(Weff + (long)(o0 + r) * K_DIM)[dc] = ov;
  }
}

// ---------------- Kernel 4: 256x256 8-phase GEMM, counted-lgkm pipelined ----------------
// Slots per operand: 4 x [128][64] bf16; tile T half h -> slot (T&1)*2+h.
// Phase k: STAGE; issue reads R(k+1) (inline asm); lgkmcnt(c_{k+1}) drains R(k);
// MFMA quad k; [vmcnt(4) at p2/p6]; barrier.  Reads execute under previous MFMA.
__global__ __launch_bounds__(512, 1)
void k_gemm256(const unsigned short* __restrict__ A,
               const unsigned short* __restrict__ Bw,
               const float* __restrict__ bias,
               float* __restrict__ C) {
  __shared__ unsigned short As[4][128][64];  // 64 KB
  __shared__ unsigned short Bs[4][128][64];  // 64 KB
  constexpr int SLOT_E = 128 * 64;

  const int t    = threadIdx.x;
  const int lane = t & 63;
  const int wave = t >> 6;
  const int wr   = wave >> 2;
  const int wc   = wave & 3;
  const int fr   = lane & 15;
  const int kq   = lane >> 4;

  const int bid = blockIdx.x;
  const int swz = (bid & 7) * 64 + (bid >> 3);
  const int brow = (swz >> 4) * 256;
  const int bcol = (swz & 15) * 256;

  const unsigned short* Ag = A  + (size_t)brow * K_DIM;
  const unsigned short* Bg = Bw + (size_t)bcol * K_DIM;

  // staging addressing (linear LDS dest, inverse-swizzled global source)
  const int i0 = t, i1 = 512 + t;
  const int r_s0 = i0 >> 3, r_s1 = i1 >> 3;
  const int c_e0 = (((i0 & 7) * 16) ^ ((r_s0 & 7) << 4)) >> 1;
  const int c_e1 = (((i1 & 7) * 16) ^ ((r_s1 & 7) << 4)) >> 1;

  unsigned short* as0 = &As[0][0][0];
  unsigned short* bs0 = &Bs[0][0][0];

  // fragment read addressing (swizzled), base VGPRs + compile-time slot/m offsets
  const int arow  = wr * 64 + fr;
  const int browl = wc * 32 + fr;
  const int axr   = (fr & 7) << 4;
  const unsigned colx0 = (unsigned)((kq * 16) ^ axr);
  const unsigned colx1 = (unsigned)((kq * 16 + 64) ^ axr);
  const unsigned aK0 = lds_addr(as0) + arow * 128 + colx0;
  const unsigned aK1 = lds_addr(as0) + arow * 128 + colx1;
  const unsigned bK0 = lds_addr(bs0) + browl * 128 + colx0;
  const unsigned bK1 = lds_addr(bs0) + browl * 128 + colx1;

#define STAGE(DST, GBASE, T_, H_) do { \
    gll16((GBASE) + (size_t)((H_) * 128 + r_s0) * K_DIM + (T_) * 64 + c_e0, (DST) + i0 * 8); \
    gll16((GBASE) + (size_t)((H_) * 128 + r_s1) * K_DIM + (T_) * 64 + c_e1, (DST) + i1 * 8); \
  } while (0)

#define RA(AR, S) do { \
    DSR(AR[0][0], aK0, (S)*16384 + 0*2048); DSR(AR[0][1], aK1, (S)*16384 + 0*2048); \
    DSR(AR[1][0], aK0, (S)*16384 + 1*2048); DSR(AR[1][1], aK1, (S)*16384 + 1*2048); \
    DSR(AR[2][0], aK0, (S)*16384 + 2*2048); DSR(AR[2][1], aK1, (S)*16384 + 2*2048); \
    DSR(AR[3][0], aK0, (S)*16384 + 3*2048); DSR(AR[3][1], aK1, (S)*16384 + 3*2048); \
  } while (0)

#define RB(BR, S) do { \
    DSR(BR[0][0], bK0, (S)*16384 + 0*2048); DSR(BR[0][1], bK1, (S)*16384 + 0*2048); \
    DSR(BR[1][0], bK0, (S)*16384 + 1*2048); DSR(BR[1][1], bK1, (S)*16384 + 1*2048); \
  } while (0)

#define QUAD(MH, NH_, AR, BR) do { \
    __builtin_amdgcn_s_setprio(1); \
    _Pragma("unroll") for (int ks = 0; ks < 2; ++ks) \
    _Pragma("unroll") for (int m = 0; m < 4; ++m) \
    _Pragma("unroll") for (int n = 0; n < 2; ++n) \
      acc[MH][NH_][m][n] = __builtin_amdgcn_mfma_f32_16x16x32_bf16(AR[m][ks], BR[n][ks], acc[MH][NH_][m][n], 0, 0, 0); \
    __builtin_amdgcn_s_setprio(0); \
    __builtin_amdgcn_sched_barrier(0); \
  } while (0)

  bf16x8 ar0[4][2], ar1[4][2];   // A-half0 / A-half1 fragments
  bf16x8 b0[2][2],  b1[2][2];    // B-half0 / B-half1 fragments
  f32x4 acc[2][2][4][2] = {};

  // ---- prologue: stage tile0 fully + tile1 (A0,B0,B1); then preload R(q0).
  STAGE(as0 + 0 * SLOT_E, Ag, 0, 0);
  STAGE(bs0 + 0 * SLOT_E, Bg, 0, 0);
  STAGE(bs0 + 1 * SLOT_E, Bg, 0, 1);
  STAGE(as0 + 1 * SLOT_E, Ag, 0, 1);
  STAGE(as0 + 2 * SLOT_E, Ag, 1, 0);
  STAGE(bs0 + 2 * SLOT_E, Bg, 1, 0);
  STAGE(bs0 + 3 * SLOT_E, Bg, 1, 1);
  VMC(6);                      // tile0's 4 half-tiles globally staged after BAR
  BAR();
  RA(ar0, 0); RB(b0, 0);       // R(q0): 12 reads outstanding

  #pragma unroll 1
  for (int it = 0; it < 31; ++it) {
    const int T = 2 * it;
    // p0: q(0,0) even; reads b1; stage A1(T+1)->A3
    STAGE(as0 + 3 * SLOT_E, Ag, T + 1, 1);
    RB(b1, 1);
    LGKM(4);  QUAD(0, 0, ar0, b0);  BAR();
    // p1: q(0,1) even; reads ar1; stage A0(T+2)->A0
    STAGE(as0 + 0 * SLOT_E, Ag, T + 2, 0);
    RA(ar1, 1);
    LGKM(8);  QUAD(0, 1, ar0, b1);  BAR();
    // p2: q(1,0) even; no reads; stage B0(T+2)->B0; vmcnt(4)
    STAGE(bs0 + 0 * SLOT_E, Bg, T + 2, 0);
    LGKM(0);  QUAD(1, 0, ar1, b0);  VMC(4);  BAR();
    // p3: q(1,1) even; reads ar0',b0' (tile T+1, slots 2); stage B1(T+2)->B1
    STAGE(bs0 + 1 * SLOT_E, Bg, T + 2, 1);
    RA(ar0, 2); RB(b0, 2);
    LGKM(12); QUAD(1, 1, ar1, b1);  BAR();
    // p4: q(0,0) odd; reads b1'; stage A1(T+2)->A1
    STAGE(as0 + 1 * SLOT_E, Ag, T + 2, 1);
    RB(b1, 3);
    LGKM(4);  QUAD(0, 0, ar0, b0);  BAR();
    // p5: q(0,1) odd; reads ar1'; stage A0(T+3)->A2
    STAGE(as0 + 2 * SLOT_E, Ag, T + 3, 0);
    RA(ar1, 3);
    LGKM(8);  QUAD(0, 1, ar0, b1);  BAR();
    // p6: q(1,0) odd; no reads; stage B0(T+3)->B2; vmcnt(4)
    STAGE(bs0 + 2 * SLOT_E, Bg, T + 3, 0);
    LGKM(0);  QUAD(1, 0, ar1, b0);  VMC(4);  BAR();
    // p7: q(1,1) odd; reads ar0,b0 for NEXT tile pair (slots 0); stage B1(T+3)->B3
    STAGE(bs0 + 3 * SLOT_E, Bg, T + 3, 1);
    RA(ar0, 0); RB(b0, 0);
    LGKM(12); QUAD(1, 1, ar1, b1);  BAR();
  }

  // ---- epilogue: tiles 62 (slots 0,1) and 63 (slots 2,3)
  STAGE(as0 + 3 * SLOT_E, Ag, 63, 1);   // A1(63)->A3 (reads of A3 drained at p6+BAR)
  VMC(0);
  BAR();
  RB(b1, 1);            LGKM(4);  QUAD(0, 0, ar0, b0);
  RA(ar1, 1);           LGKM(8);  QUAD(0, 1, ar0, b1);
                        LGKM(0);  QUAD(1, 0, ar1, b0);
  RA(ar0, 2); RB(b0, 2); LGKM(12); QUAD(1, 1, ar1, b1);
  RB(b1, 3);            LGKM(4);  QUAD(0, 0, ar0, b0);
  RA(ar1, 3);           LGKM(8);  QUAD(0, 1, ar0, b1);
                        LGKM(0);  QUAD(1, 0, ar1, b0);
                        LGKM(0);  QUAD(1, 1, ar1, b1);

#undef STAGE
#undef RA
#undef RB
#undef QUAD

  // ---- C write: C/D layout col=lane&15, row=4*(lane>>4)+reg (m89-verified)
  const int crow = brow + wr * 64 + kq * 4;
  const int ccol = bcol + wc * 32 + fr;
  #pragma unroll
  for (int mh = 0; mh < 2; ++mh)
  #pragma unroll
  for (int nh = 0; nh < 2; ++nh)
  #pragma unroll
  for (int m = 0; m < 4; ++m)
  #pragma unroll
  for (int n = 0; n < 2; ++n) {
    const int col = ccol + nh * 128 + n * 16;
    const float bv = bias[col];
    #pragma unroll
    for (int r = 0; r < 4; ++r)
      C[(size_t)(crow + mh * 128 + m * 16 + r) * N_DIM + col] = acc[mh][nh][m][n][r] + bv;
  }
}

// ---------------- launch ----------------
extern "C" void kernel_launch(void* const* d_in, const int* in_sizes, int n_in,
                              void* d_out, int out_size, void* d_ws, size_t ws_size,
                              hipStream_t stream) {
  const float* x  = (const float*)d_in[0];
  const float* W  = (const float*)d_in[1];
  const float* bv = (const float*)d_in[2];
  const float* Am = (const float*)d_in[3];
  const float* Hm = (const float*)d_in[4];
  const float* Bm = (const float*)d_in[5];
  const float* sv = (const float*)d_in[6];
  float* out = (float*)d_out;

  char* ws = (char*)d_ws;
  unsigned short* xbf  = (unsigned short*)ws;                                 // 64 MB
  unsigned short* weff = (unsigned short*)(ws + (size_t)M_DIM * K_DIM * 2);   // 32 MB
  float* ha = (float*)(ws + (size_t)M_DIM * K_DIM * 2 + (size_t)N_DIM * K_DIM * 2); // 2 MB

  k_cast_bf16<<<(M_DIM * K_DIM / 4 + 255) / 256, 256, 0, stream>>>(x, xbf, M_DIM * K_DIM / 4);
  k_ha<<<(NH * R_DIM * (K_DIM / 4)) / 256, 256, 0, stream>>>(Am, Hm, sv, ha);
  k_weff<<<dim3(N_DIM / 8, 4), 256, 0, stream>>>(W, Bm, ha, weff);
  k_gemm256<<<dim3(512), 512, 0, stream>>>(xbf, weff, bv, out);
}

// Round 5
// 305.233 us; speedup vs baseline: 1.4821x; 1.4821x over previous
//
#include <hip/hip_runtime.h>
#include <hip/hip_bf16.h>

typedef __attribute__((ext_vector_type(4))) float f32x4;
typedef __attribute__((ext_vector_type(8))) short bf16x8;

#define M_DIM 8192
#define N_DIM 4096
#define K_DIM 4096
#define NH 8
#define R_DIM 16
#define HQ 128          // NH * R_DIM

__device__ __forceinline__ unsigned short f2bf(float f) {
  union { float f; unsigned int u; } v; v.f = f;
  unsigned int r = v.u + 0x7fffu + ((v.u >> 16) & 1u);  // RNE
  return (unsigned short)(r >> 16);
}

__device__ __forceinline__ void gll16(const void* gptr, void* lptr) {
  __builtin_amdgcn_global_load_lds(
      (const __attribute__((address_space(1))) void*)gptr,
      (__attribute__((address_space(3))) void*)lptr, 16, 0, 0);
}

#define FENCE() asm volatile("" ::: "memory")
#define BAR() do { FENCE(); __builtin_amdgcn_s_barrier(); FENCE(); } while (0)

// ---------------- Kernel 1: cast x (f32) -> bf16 ----------------
__global__ void k_cast_bf16(const float* __restrict__ in,
                            unsigned short* __restrict__ out, int n4) {
  int i = blockIdx.x * 256 + threadIdx.x;
  if (i >= n4) return;
  float4 v = reinterpret_cast<const float4*>(in)[i];
  ushort4 o;
  o.x = f2bf(v.x); o.y = f2bf(v.y); o.z = f2bf(v.z); o.w = f2bf(v.w);
  reinterpret_cast<ushort4*>(out)[i] = o;
}

// ---------------- Kernel 2a: HA_T[d][h*16+q] = bf16( s[h] * sum_r H[h][q][r]*A[h][r][d] )
// grid (16, 8): blockIdx.y = h; 256 threads over d.
__global__ void k_ha_t(const float* __restrict__ A, const float* __restrict__ H,
                       const float* __restrict__ s, unsigned short* __restrict__ HA_T) {
  const int d = blockIdx.x * 256 + threadIdx.x;
  const int h = blockIdx.y;
  const float* Ah = A + (size_t)h * R_DIM * K_DIM;
  const float* Hh = H + h * R_DIM * R_DIM;
  const float sv = s[h];
  float acc[R_DIM];
  #pragma unroll
  for (int q = 0; q < R_DIM; ++q) acc[q] = 0.f;
  #pragma unroll
  for (int r = 0; r < R_DIM; ++r) {
    float a = Ah[(size_t)r * K_DIM + d];
    #pragma unroll
    for (int q = 0; q < R_DIM; ++q) acc[q] += Hh[q * R_DIM + r] * a;
  }
  unsigned short o[R_DIM];
  #pragma unroll
  for (int q = 0; q < R_DIM; ++q) o[q] = f2bf(acc[q] * sv);
  // 16 bf16 = 32 B contiguous
  *reinterpret_cast<uint4*>(&HA_T[(size_t)d * HQ + h * R_DIM]) = *reinterpret_cast<uint4*>(o);
  *reinterpret_cast<uint4*>(&HA_T[(size_t)d * HQ + h * R_DIM + 8]) = *reinterpret_cast<uint4*>(o + 8);
}

// ---------------- Kernel 2b: Bc[o][h*16+q] = bf16( B[h][o][q] )
// block = 256 threads = 16 o x 16 q; grid = 4096/16 = 256.
__global__ void k_bcat(const float* __restrict__ Bm, unsigned short* __restrict__ Bc) {
  const int t = threadIdx.x;
  const int ol = t >> 4, q = t & 15;
  const int o = blockIdx.x * 16 + ol;
  #pragma unroll
  for (int h = 0; h < NH; ++h)
    Bc[(size_t)o * HQ + h * R_DIM + q] = f2bf(Bm[((size_t)h * N_DIM + o) * R_DIM + q]);
}

// ---------------- Kernel 3: Weff[o][d] = bf16( W[o][d] + Bc[o][:] @ HA_T[d][:]^T )
// MFMA GEMM, M=N=4096, K=128.  128x128 tile, BK=32, 4 waves (2x2).  (round-1 structure)
__global__ __launch_bounds__(256)
void k_weff_mfma(const unsigned short* __restrict__ Ab,   // Bc [4096][128]
                 const unsigned short* __restrict__ Bb,   // HA_T [4096][128]
                 const float* __restrict__ W,
                 unsigned short* __restrict__ Weff) {
  constexpr int WK = HQ;  // 128
  __shared__ unsigned short As[128 * 32];
  __shared__ unsigned short Bs[128 * 32];

  const int t = threadIdx.x;
  const int lane = t & 63;
  const int wave = t >> 6;
  const int wr = wave >> 1, wc = wave & 1;
  const int brow = blockIdx.y * 128;
  const int bcol = blockIdx.x * 128;

  const int r0 = t >> 2, ch = t & 3;
  const size_t a_off0 = (size_t)(brow + r0) * WK + ch * 8;
  const size_t a_off1 = (size_t)(brow + r0 + 64) * WK + ch * 8;
  const size_t b_off0 = (size_t)(bcol + r0) * WK + ch * 8;
  const size_t b_off1 = (size_t)(bcol + r0 + 64) * WK + ch * 8;
  unsigned short* as_d0 = As + t * 8;
  unsigned short* as_d1 = As + (t + 256) * 8;
  unsigned short* bs_d0 = Bs + t * 8;
  unsigned short* bs_d1 = Bs + (t + 256) * 8;

  const int fr = lane & 15;
  const int kk = (lane >> 4) * 8;

  f32x4 acc[4][4] = {};

  for (int k0 = 0; k0 < WK; k0 += 32) {
    gll16(Ab + a_off0 + k0, as_d0);
    gll16(Ab + a_off1 + k0, as_d1);
    gll16(Bb + b_off0 + k0, bs_d0);
    gll16(Bb + b_off1 + k0, bs_d1);
    __syncthreads();

    bf16x8 af[4], bfr[4];
    #pragma unroll
    for (int m = 0; m < 4; ++m)
      af[m] = *reinterpret_cast<const bf16x8*>(&As[(wr * 64 + m * 16 + fr) * 32 + kk]);
    #pragma unroll
    for (int n = 0; n < 4; ++n)
      bfr[n] = *reinterpret_cast<const bf16x8*>(&Bs[(wc * 64 + n * 16 + fr) * 32 + kk]);

    #pragma unroll
    for (int m = 0; m < 4; ++m)
      #pragma unroll
      for (int n = 0; n < 4; ++n)
        acc[m][n] = __builtin_amdgcn_mfma_f32_16x16x32_bf16(af[m], bfr[n], acc[m][n], 0, 0, 0);

    __syncthreads();
  }

  const int crow0 = brow + wr * 64 + (lane >> 4) * 4;
  const int ccol0 = bcol + wc * 64 + fr;
  #pragma unroll
  for (int m = 0; m < 4; ++m)
    #pragma unroll
    for (int n = 0; n < 4; ++n) {
      const int col = ccol0 + n * 16;
      #pragma unroll
      for (int r = 0; r < 4; ++r) {
        const size_t idx = (size_t)(crow0 + m * 16 + r) * N_DIM + col;
        Weff[idx] = f2bf(acc[m][n][r] + W[idx]);
      }
    }
}

// ---------------- Kernel 4: 256x256 8-phase GEMM (round-3 + single barrier/phase) ----
// Slots per operand: 4 x [128][64] bf16; tile T half h -> slot (T&1)*2+h.
// Phase: {LOAD (C++ ds_reads); STAGE; MFMA quad; [vmcnt(6) at p3/p7]; BAR}.
// Hazard ledger: stage(p) slot disjoint from read(p) slot for all p; reads drain
// before own MFMA (data dep) which precedes phase-end BAR; vmcnt(6)@p3 drains
// stages through p0 (covers p4/p5/p6 reads), @p7 drains through p4 (covers next
// p0/p1/p2 reads).  LDS swizzle: linear dest + inverse-swizzled global source.
__global__ __launch_bounds__(512, 2)
void k_gemm256(const unsigned short* __restrict__ A,
               const unsigned short* __restrict__ Bw,
               const float* __restrict__ bias,
               float* __restrict__ C) {
  __shared__ unsigned short As[4][128][64];  // 64 KB
  __shared__ unsigned short Bs[4][128][64];  // 64 KB
  constexpr int SLOT_E = 128 * 64;

  const int t    = threadIdx.x;
  const int lane = t & 63;
  const int wave = t >> 6;
  const int wr   = wave >> 2;
  const int wc   = wave & 3;
  const int fr   = lane & 15;
  const int kq   = lane >> 4;

  const int bid = blockIdx.x;
  const int swz = (bid & 7) * 64 + (bid >> 3);
  const int brow = (swz >> 4) * 256;
  const int bcol = (swz & 15) * 256;

  const unsigned short* Ag = A  + (size_t)brow * K_DIM;
  const unsigned short* Bg = Bw + (size_t)bcol * K_DIM;

  const int i0 = t, i1 = 512 + t;
  const int r_s0 = i0 >> 3, r_s1 = i1 >> 3;
  const int c_e0 = (((i0 & 7) * 16) ^ ((r_s0 & 7) << 4)) >> 1;
  const int c_e1 = (((i1 & 7) * 16) ^ ((r_s1 & 7) << 4)) >> 1;

  unsigned short* as0 = &As[0][0][0];
  unsigned short* bs0 = &Bs[0][0][0];
  const char* lds_a = (const char*)as0;
  const char* lds_b = (const char*)bs0;

  const int arow = wr * 64 + fr;
  const int browl = wc * 32 + fr;
  const int axr = (fr & 7) << 4;

#define STAGE(DST, GBASE, T_, H_) do { \
    gll16((GBASE) + (size_t)((H_) * 128 + r_s0) * K_DIM + (T_) * 64 + c_e0, (DST) + i0 * 8); \
    gll16((GBASE) + (size_t)((H_) * 128 + r_s1) * K_DIM + (T_) * 64 + c_e1, (DST) + i1 * 8); \
  } while (0)

#define LOAD_A(SLOT) do { \
    _Pragma("unroll") for (int m = 0; m < 4; ++m) \
    _Pragma("unroll") for (int ks = 0; ks < 2; ++ks) \
      ar[m][ks] = *(const bf16x8*)(lds_a + (SLOT) * 16384 + (arow + m * 16) * 128 + ((kq * 16 + ks * 64) ^ axr)); \
  } while (0)

#define LOAD_B(SLOT, BR) do { \
    _Pragma("unroll") for (int n = 0; n < 2; ++n) \
    _Pragma("unroll") for (int ks = 0; ks < 2; ++ks) \
      BR[n][ks] = *(const bf16x8*)(lds_b + (SLOT) * 16384 + (browl + n * 16) * 128 + ((kq * 16 + ks * 64) ^ axr)); \
  } while (0)

#define MFMA_QUAD(MH, NHX, BR) do { \
    __builtin_amdgcn_s_setprio(1); \
    _Pragma("unroll") for (int m = 0; m < 4; ++m) \
    _Pragma("unroll") for (int n = 0; n < 2; ++n) \
    _Pragma("unroll") for (int ks = 0; ks < 2; ++ks) \
      acc[MH][NHX][m][n] = __builtin_amdgcn_mfma_f32_16x16x32_bf16(ar[m][ks], BR[n][ks], acc[MH][NHX][m][n], 0, 0, 0); \
    __builtin_amdgcn_s_setprio(0); \
  } while (0)

  bf16x8 ar[4][2];
  bf16x8 b0r[2][2];
  bf16x8 b1r[2][2];
  f32x4 acc[2][2][4][2] = {};

  // ---- prologue: tile0 fully + tile1 (A0,B0,B1)
  STAGE(as0 + 0 * SLOT_E, Ag, 0, 0);
  STAGE(bs0 + 0 * SLOT_E, Bg, 0, 0);
  STAGE(bs0 + 1 * SLOT_E, Bg, 0, 1);
  STAGE(as0 + 1 * SLOT_E, Ag, 0, 1);
  STAGE(as0 + 2 * SLOT_E, Ag, 1, 0);
  STAGE(bs0 + 2 * SLOT_E, Bg, 1, 0);
  STAGE(bs0 + 3 * SLOT_E, Bg, 1, 1);
  asm volatile("s_waitcnt vmcnt(6)" ::: "memory");
  __builtin_amdgcn_s_barrier();
  FENCE();

  #pragma unroll 1
  for (int it = 0; it < 31; ++it) {
    const int T = 2 * it;
    // p0
    LOAD_A(0); LOAD_B(0, b0r);
    STAGE(as0 + 3 * SLOT_E, Ag, T + 1, 1);
    MFMA_QUAD(0, 0, b0r); BAR();
    // p1
    LOAD_B(1, b1r);
    STAGE(as0 + 0 * SLOT_E, Ag, T + 2, 0);
    MFMA_QUAD(0, 1, b1r); BAR();
    // p2
    LOAD_A(1);
    STAGE(bs0 + 0 * SLOT_E, Bg, T + 2, 0);
    MFMA_QUAD(1, 0, b0r); BAR();
    // p3
    STAGE(bs0 + 1 * SLOT_E, Bg, T + 2, 1);
    MFMA_QUAD(1, 1, b1r);
    asm volatile("s_waitcnt vmcnt(6)" ::: "memory");
    BAR();
    // p4
    LOAD_A(2); LOAD_B(2, b0r);
    STAGE(as0 + 1 * SLOT_E, Ag, T + 2, 1);
    MFMA_QUAD(0, 0, b0r); BAR();
    // p5
    LOAD_B(3, b1r);
    STAGE(as0 + 2 * SLOT_E, Ag, T + 3, 0);
    MFMA_QUAD(0, 1, b1r); BAR();
    // p6
    LOAD_A(3);
    STAGE(bs0 + 2 * SLOT_E, Bg, T + 3, 0);
    MFMA_QUAD(1, 0, b0r); BAR();
    // p7
    STAGE(bs0 + 3 * SLOT_E, Bg, T + 3, 1);
    MFMA_QUAD(1, 1, b1r);
    asm volatile("s_waitcnt vmcnt(6)" ::: "memory");
    BAR();
  }

  // ---- epilogue: tiles 62 (slots 0,1) and 63 (slots 2,3)
  STAGE(as0 + 3 * SLOT_E, Ag, 63, 1);
  asm volatile("s_waitcnt vmcnt(0)" ::: "memory");
  __builtin_amdgcn_s_barrier();
  FENCE();
  LOAD_A(0); LOAD_B(0, b0r); MFMA_QUAD(0, 0, b0r);
  LOAD_B(1, b1r);            MFMA_QUAD(0, 1, b1r);
  LOAD_A(1);                 MFMA_QUAD(1, 0, b0r);
                             MFMA_QUAD(1, 1, b1r);
  LOAD_A(2); LOAD_B(2, b0r); MFMA_QUAD(0, 0, b0r);
  LOAD_B(3, b1r);            MFMA_QUAD(0, 1, b1r);
  LOAD_A(3);                 MFMA_QUAD(1, 0, b0r);
                             MFMA_QUAD(1, 1, b1r);

#undef STAGE
#undef LOAD_A
#undef LOAD_B
#undef MFMA_QUAD

  const int crow = brow + wr * 64 + kq * 4;
  const int ccol = bcol + wc * 32 + fr;
  #pragma unroll
  for (int mh = 0; mh < 2; ++mh)
  #pragma unroll
  for (int nh = 0; nh < 2; ++nh)
  #pragma unroll
  for (int m = 0; m < 4; ++m)
  #pragma unroll
  for (int n = 0; n < 2; ++n) {
    const int col = ccol + nh * 128 + n * 16;
    const float bv = bias[col];
    #pragma unroll
    for (int r = 0; r < 4; ++r)
      C[(size_t)(crow + mh * 128 + m * 16 + r) * N_DIM + col] = acc[mh][nh][m][n][r] + bv;
  }
}

// ---------------- launch ----------------
extern "C" void kernel_launch(void* const* d_in, const int* in_sizes, int n_in,
                              void* d_out, int out_size, void* d_ws, size_t ws_size,
                              hipStream_t stream) {
  const float* x  = (const float*)d_in[0];
  const float* W  = (const float*)d_in[1];
  const float* bv = (const float*)d_in[2];
  const float* Am = (const float*)d_in[3];
  const float* Hm = (const float*)d_in[4];
  const float* Bm = (const float*)d_in[5];
  const float* sv = (const float*)d_in[6];
  float* out = (float*)d_out;

  char* ws = (char*)d_ws;
  unsigned short* xbf  = (unsigned short*)ws;                                 // 64 MB
  unsigned short* weff = (unsigned short*)(ws + (size_t)M_DIM * K_DIM * 2);   // 32 MB
  unsigned short* hat  = (unsigned short*)(ws + (size_t)(M_DIM + N_DIM) * K_DIM * 2);          // 1 MB
  unsigned short* bc   = (unsigned short*)(ws + (size_t)(M_DIM + N_DIM) * K_DIM * 2 + (size_t)N_DIM * HQ * 2); // 1 MB

  k_cast_bf16<<<(M_DIM * K_DIM / 4 + 255) / 256, 256, 0, stream>>>(x, xbf, M_DIM * K_DIM / 4);
  k_ha_t<<<dim3(K_DIM / 256, NH), 256, 0, stream>>>(Am, Hm, sv, hat);
  k_bcat<<<N_DIM / 16, 256, 0, stream>>>(Bm, bc);
  k_weff_mfma<<<dim3(N_DIM / 128, N_DIM / 128), 256, 0, stream>>>(bc, hat, W, weff);
  k_gemm256<<<dim3(512), 512, 0, stream>>>(xbf, weff, bv, out);
}